// Round 2
// baseline (287.432 us; speedup 1.0000x reference)
//
#include <hip/hip_runtime.h>
#include <hip/hip_bf16.h>

// TopKPool: B=128, K=512, D=768, topk=8 (all derived from in_sizes at launch).
// Outputs (concatenated fp32): pooled (B,D), attn_weights (B,K).

// ---------------- Kernel 1: masked linear scores ----------------
// One wave (64 lanes) per (b,k) row. float4 loads: D/4 float4 per row,
// lane p reads e4[p], p += 64. Fully coalesced 16B/lane.
__global__ __launch_bounds__(256) void topkpool_scores_kernel(
    const float* __restrict__ emb, const int* __restrict__ mask,
    const float* __restrict__ w, const float* __restrict__ bias,
    float* __restrict__ scores, int rows, int D)
{
    const int wave = threadIdx.x >> 6;
    const int lane = threadIdx.x & 63;
    const int r = blockIdx.x * 4 + wave;
    if (r >= rows) return;

    const float4* __restrict__ e4 = reinterpret_cast<const float4*>(emb + (size_t)r * D);
    const float4* __restrict__ w4 = reinterpret_cast<const float4*>(w);
    const int D4 = D >> 2;  // D is a multiple of 4 (768)

    float sum = 0.f;
    for (int p = lane; p < D4; p += 64) {
        float4 a = e4[p];
        float4 b = w4[p];
        sum += a.x * b.x + a.y * b.y + a.z * b.z + a.w * b.w;
    }
    // wave-64 butterfly reduce
    #pragma unroll
    for (int off = 32; off; off >>= 1) sum += __shfl_xor(sum, off, 64);

    if (lane == 0) {
        float s = sum + bias[0];
        if (mask[r] == 0) s = -1e30f;  // NEG_INF per reference
        scores[r] = s;
    }
}

// ---------------- Kernel 2: top-k select + pool + attn weights ----------------
// One block (256 threads) per batch row b.
#define TKP_MAXK 2048
__global__ __launch_bounds__(256) void topkpool_select_kernel(
    const float* __restrict__ emb, const float* __restrict__ scores,
    const int* __restrict__ topk_ptr, float* __restrict__ pooled,
    float* __restrict__ attn, int K, int D)
{
    __shared__ float s_sc[TKP_MAXK];
    __shared__ int   sel[TKP_MAXK];
    __shared__ float rv[256];
    __shared__ int   ri[256];

    const int b = blockIdx.x;
    const int t = threadIdx.x;

    int k = topk_ptr[0];
    if (k > K) k = K;
    if (k < 1) k = 1;

    for (int j = t; j < K; j += 256) s_sc[j] = scores[(size_t)b * K + j];
    __syncthreads();

    // Iterative argmax: k rounds, tie-break to the LOWER index (lax.top_k semantics).
    for (int i = 0; i < k; ++i) {
        float bv = -3.402823466e38f;
        int   bi = 0x7fffffff;
        for (int j = t; j < K; j += 256) {
            float v = s_sc[j];
            if (v > bv) { bv = v; bi = j; }   // j ascending -> lower index wins ties
        }
        rv[t] = bv; ri[t] = bi;
        __syncthreads();
        #pragma unroll
        for (int s = 128; s; s >>= 1) {
            if (t < s) {
                float ov = rv[t + s]; int oi = ri[t + s];
                if (ov > rv[t] || (ov == rv[t] && oi < ri[t])) { rv[t] = ov; ri[t] = oi; }
            }
            __syncthreads();
        }
        if (t == 0) {
            sel[i] = ri[0];
            s_sc[ri[0]] = -3.402823466e38f;  // exclude from next rounds
        }
        __syncthreads();
    }

    const float inv_k = 1.0f / (float)k;

    // attn weights: zero the row, then scatter 1/k at selected indices.
    for (int j = t; j < K; j += 256) attn[(size_t)b * K + j] = 0.f;
    __syncthreads();
    for (int i = t; i < k; i += 256) attn[(size_t)b * K + sel[i]] = inv_k;

    // pooled: mean of the k selected embedding rows. Coalesced across d.
    for (int d = t; d < D; d += 256) {
        float acc = 0.f;
        for (int i = 0; i < k; ++i) acc += emb[((size_t)b * K + sel[i]) * D + d];
        pooled[(size_t)b * D + d] = acc * inv_k;
    }
}

extern "C" void kernel_launch(void* const* d_in, const int* in_sizes, int n_in,
                              void* d_out, int out_size, void* d_ws, size_t ws_size,
                              hipStream_t stream) {
    const float* emb   = (const float*)d_in[0];
    const int*   mask  = (const int*)d_in[1];
    const float* w     = (const float*)d_in[2];
    const float* bias  = (const float*)d_in[3];
    const int*   topk  = (const int*)d_in[4];

    const int BK = in_sizes[1];           // B*K
    const int D  = in_sizes[0] / BK;      // 768
    const int B  = (out_size - BK) / D;   // out_size = B*D + B*K
    const int K  = BK / B;                // 512

    float* scores = (float*)d_ws;                    // B*K floats of scratch
    float* pooled = (float*)d_out;                   // (B, D)
    float* attn   = (float*)d_out + (size_t)B * D;   // (B, K)

    const int blocks1 = (BK + 3) / 4;  // 4 waves per block, 1 row per wave
    topkpool_scores_kernel<<<blocks1, 256, 0, stream>>>(emb, mask, w, bias, scores, BK, D);
    topkpool_select_kernel<<<B, 256, 0, stream>>>(emb, scores, topk, pooled, attn, K, D);
}